// Round 3
// baseline (531.450 us; speedup 1.0000x reference)
//
#include <hip/hip_runtime.h>
#include <math.h>

#define H 4096
#define NE 64
#define KTOP 8
#define BT 32
#define KC 32
#define TTOT 16384
#define NBLK (TTOT / BT)        // 512
#define NCHUNK (H / KC)         // 128
#define TAU 1e-4f
#define DELTA 1e-3f

struct __align__(16) Smem1 {
  union {
    struct { float xs[32][32]; float we[64][32]; };   // 12 KB staging
    float lg[32 * 66];                                // 8448 B logits
  };
  float msum[8][64];
  float cnt[8][64];
};

// Pass 1: fp32 router GEMM + top-9 + flag/mask + fp32 outputs + aux partials.
__global__ __launch_bounds__(512) void moe_pass1(
    const float* __restrict__ x, const float* __restrict__ w,
    float* __restrict__ out, unsigned int* __restrict__ wmask,
    float* __restrict__ waux) {
  __shared__ Smem1 sm;
  const int tid = threadIdx.x;
  const int bid = blockIdx.x;
  const int tok0 = bid * BT;

  const int tr = tid >> 5;                  // 0..15 (2 tokens each)
  const int tc = tid & 31;                  // 0..31 (2 experts each)
  const int swzr = ((tc >> 2) & 7) << 2;    // read-side swizzle (same for j=0,1)

  // staging: all 512 threads load one w float4; threads <256 also one x float4
  const int srow = tid >> 3;                // 0..63
  const int scol = (tid & 7) * 4;
  const int wswz = ((srow >> 3) & 7) << 2;
  const float* wp = w + (size_t)srow * H + scol;
  const bool xload = tid < 256;
  const int xrow = tid >> 3;                // 0..31 when xload
  const float* xp = x + (size_t)(tok0 + xrow) * H + scol;

  float acc[2][2] = {{0.f, 0.f}, {0.f, 0.f}};

  // prologue: stage chunk 0
  {
    float4 wv = *(const float4*)wp;
    *(float4*)&sm.we[srow][scol ^ wswz] = wv;
    if (xload) {
      float4 xv = *(const float4*)xp;
      *(float4*)&sm.xs[xrow][scol] = xv;
    }
  }
  __syncthreads();

#pragma unroll 1
  for (int c = 0; c < NCHUNK; ++c) {
    float4 wn, xn;
    const bool more = (c + 1) < NCHUNK;
    if (more) {  // register prefetch; latency hidden under FMAs
      wn = *(const float4*)(wp + (c + 1) * KC);
      if (xload) xn = *(const float4*)(xp + (c + 1) * KC);
    }
#pragma unroll
    for (int kq = 0; kq < 8; ++kq) {
      float4 xv0 = *(const float4*)&sm.xs[tr * 2 + 0][kq * 4];
      float4 xv1 = *(const float4*)&sm.xs[tr * 2 + 1][kq * 4];
      float4 wv0 = *(const float4*)&sm.we[tc * 2 + 0][(kq * 4) ^ swzr];
      float4 wv1 = *(const float4*)&sm.we[tc * 2 + 1][(kq * 4) ^ swzr];
      acc[0][0] += xv0.x * wv0.x; acc[0][1] += xv0.x * wv1.x;
      acc[1][0] += xv1.x * wv0.x; acc[1][1] += xv1.x * wv1.x;
      acc[0][0] += xv0.y * wv0.y; acc[0][1] += xv0.y * wv1.y;
      acc[1][0] += xv1.y * wv0.y; acc[1][1] += xv1.y * wv1.y;
      acc[0][0] += xv0.z * wv0.z; acc[0][1] += xv0.z * wv1.z;
      acc[1][0] += xv1.z * wv0.z; acc[1][1] += xv1.z * wv1.z;
      acc[0][0] += xv0.w * wv0.w; acc[0][1] += xv0.w * wv1.w;
      acc[1][0] += xv1.w * wv0.w; acc[1][1] += xv1.w * wv1.w;
    }
    __syncthreads();
    if (more) {
      *(float4*)&sm.we[srow][scol ^ wswz] = wn;
      if (xload) *(float4*)&sm.xs[xrow][scol] = xn;
    }
    __syncthreads();
  }

  // spill logits (union reuse is safe: all staging reads done)
#pragma unroll
  for (int i = 0; i < 2; ++i)
#pragma unroll
    for (int j = 0; j < 2; ++j)
      sm.lg[(tr * 2 + i) * 66 + tc * 2 + j] = acc[i][j];
  __syncthreads();

  // epilogue: 8 waves x 4 tokens, lane = expert
  const int lane = tid & 63;
  const int wid = tid >> 6;
  float msum = 0.f;
  int cnt = 0;

#pragma unroll 1
  for (int it = 0; it < 4; ++it) {
    const int t = wid * 4 + it;
    const float lf = sm.lg[t * 66 + lane];

    // fp32 softmax (aux partials)
    float m = lf;
#pragma unroll
    for (int off = 32; off; off >>= 1) m = fmaxf(m, __shfl_xor(m, off));
    float p = expf(lf - m);
    float s = p;
#pragma unroll
    for (int off = 32; off; off >>= 1) s += __shfl_xor(s, off);
    msum += p / s;

    // top-9 by logit, descending, tie -> lowest index
    float cur = lf;
    float myv = 0.f;
    int myi = 0;
#pragma unroll
    for (int r = 0; r < 9; ++r) {
      float v = cur;
      int ix = lane;
#pragma unroll
      for (int off = 1; off < 64; off <<= 1) {
        float ov = __shfl_xor(v, off);
        int oi = __shfl_xor(ix, off);
        if (ov > v || (ov == v && oi < ix)) { v = ov; ix = oi; }
      }
      if (lane == r) { myv = v; myi = ix; }
      if (r < 8 && lane == ix) { cur = -INFINITY; ++cnt; }
    }

    // weights: exp(l - m0) / sum_top8 (full-softmax denominator cancels)
    const float m0 = __shfl(myv, 0);
    float e = expf(myv - m0);
    float sv = e;
    sv += __shfl_xor(sv, 1);
    sv += __shfl_xor(sv, 2);
    sv += __shfl_xor(sv, 4);
    const float wgt = e / sv;
    const int tg = tok0 + t;
    if (lane < KTOP) {
      out[(size_t)tg * KTOP + lane] = (float)myi;
      out[(size_t)TTOT * KTOP + (size_t)tg * KTOP + lane] = wgt;
    }

    // ambiguity flag: any adjacent gap among ranks 0..8 below TAU
    const float nxt = __shfl(myv, (lane + 1) & 63);
    const bool gp = (lane < 8) && (myv - nxt < TAU);
    const unsigned long long anyg = __ballot(gp);
    // candidate mask: experts within DELTA of the 8th-largest logit
    const float v7 = __shfl(myv, 7);
    const unsigned long long msk = __ballot(lf >= v7 - DELTA);
    if (lane == 0) {
      const unsigned long long mv = anyg ? msk : 0ULL;
      wmask[tg] = (unsigned)mv;
      wmask[TTOT + tg] = (unsigned)(mv >> 32);
    }
  }

  sm.msum[wid][lane] = msum;
  sm.cnt[wid][lane] = (float)cnt;
  __syncthreads();
  if (tid < 64) {
    float c8 = 0.f, m8 = 0.f;
#pragma unroll
    for (int k = 0; k < 8; ++k) { c8 += sm.cnt[k][tid]; m8 += sm.msum[k][tid]; }
    waux[bid * 128 + tid] = c8;
    waux[bid * 128 + 64 + tid] = m8;
  }
}

// Pass 2: fp64 recompute of candidate experts for flagged tokens only.
__global__ __launch_bounds__(256) void moe_pass2(
    const float* __restrict__ x, const float* __restrict__ w,
    const unsigned int* __restrict__ wmask, float* __restrict__ out) {
  __shared__ double red[4];
  __shared__ double cval[64];
  __shared__ int cidx[64];
  const int tid = threadIdx.x;
  const int lane = tid & 63, wid = tid >> 6;
  const int t0 = blockIdx.x * BT;

#pragma unroll 1
  for (int tt = 0; tt < BT; ++tt) {
    const int t = t0 + tt;
    const unsigned lo = wmask[t], hi = wmask[TTOT + t];
    if (!(lo | hi)) continue;  // uniform branch
    const unsigned long long m = ((unsigned long long)hi << 32) | lo;
    const float* xr = x + (size_t)t * H;
    int ncand = 0;
#pragma unroll 1
    for (int e = 0; e < 64; ++e) {
      if (!((m >> e) & 1ULL)) continue;  // uniform
      const float* wr = w + (size_t)e * H;
      double d = 0.0;
#pragma unroll
      for (int q = 0; q < 16; ++q) {
        const int k = tid + 256 * q;
        d = fma((double)xr[k], (double)wr[k], d);
      }
#pragma unroll
      for (int off = 32; off; off >>= 1) d += __shfl_xor(d, off);
      if (lane == 0) red[wid] = d;
      __syncthreads();
      if (tid == 0) {
        cval[ncand] = red[0] + red[1] + red[2] + red[3];
        cidx[ncand] = e;
      }
      __syncthreads();
      ++ncand;
    }
    if (tid == 0) {
      double sel[8];
      int si[8];
      for (int r = 0; r < 8; ++r) {
        int best = 0;
        double bv = -1e300;
        for (int c2 = 0; c2 < ncand; ++c2)
          if (cval[c2] > bv) { bv = cval[c2]; best = c2; }  // tie -> first = lowest e
        sel[r] = cval[best]; si[r] = cidx[best];
        cval[best] = -1e301;
      }
      const double m0 = sel[0];
      float es[8], ssum = 0.f;
      for (int r = 0; r < 8; ++r) { es[r] = expf((float)(sel[r] - m0)); ssum += es[r]; }
      for (int r = 0; r < 8; ++r) {
        out[(size_t)t * KTOP + r] = (float)si[r];
        out[(size_t)TTOT * KTOP + (size_t)t * KTOP + r] = es[r] / ssum;
      }
    }
    __syncthreads();
  }
}

// aux = alpha * mean_b sum_e (count[b,e]/(S*K/E)) * (scoresum[b,e]/S)
__global__ __launch_bounds__(256) void moe_gate_aux(
    const float* __restrict__ waux, float* __restrict__ out) {
  const int tid = threadIdx.x;
  const int b = tid >> 6, e = tid & 63;
  float cnt = 0.f, ms = 0.f;
#pragma unroll 4
  for (int j = 0; j < 128; ++j) {
    const int blk = b * 128 + j;
    cnt += waux[blk * 128 + e];
    ms += waux[blk * 128 + 64 + e];
  }
  float term = (cnt * (1.f / 512.f)) * (ms * (1.f / 4096.f));
  __shared__ float red[4];
#pragma unroll
  for (int off = 32; off; off >>= 1) term += __shfl_xor(term, off);
  if ((tid & 63) == 0) red[tid >> 6] = term;
  __syncthreads();
  if (tid == 0) {
    float tot = red[0] + red[1] + red[2] + red[3];
    out[(size_t)TTOT * KTOP * 2] = tot * (0.001f / 4.f);
  }
}

extern "C" void kernel_launch(void* const* d_in, const int* in_sizes, int n_in,
                              void* d_out, int out_size, void* d_ws, size_t ws_size,
                              hipStream_t stream) {
  (void)in_sizes; (void)n_in; (void)out_size; (void)ws_size;
  const float* x = (const float*)d_in[0];
  const float* w = (const float*)d_in[1];
  float* out = (float*)d_out;
  unsigned int* wmask = (unsigned int*)d_ws;                      // 2*TTOT u32 = 128 KB
  float* waux = (float*)((char*)d_ws + (size_t)2 * TTOT * 4);     // NBLK*128 f32 = 256 KB
  moe_pass1<<<NBLK, 512, 0, stream>>>(x, w, out, wmask, waux);
  moe_pass2<<<NBLK, 256, 0, stream>>>(x, w, wmask, out);
  moe_gate_aux<<<1, 256, 0, stream>>>(waux, out);
}